// Round 9
// baseline (267.456 us; speedup 1.0000x reference)
//
#include <hip/hip_runtime.h>
#include <hip/hip_bf16.h>

typedef __hip_bfloat16 bf16;
typedef __attribute__((ext_vector_type(8))) short short8;
typedef __attribute__((ext_vector_type(4))) float f32x4;
typedef __attribute__((ext_vector_type(16))) float f32x16;

__device__ __forceinline__ float b2f(bf16 v) { return __bfloat162float(v); }
__device__ __forceinline__ bf16  f2b(float v) { return __float2bfloat16(v); }

// ---------------------------------------------------------------------------
// Kernel 0: convert weights f32 -> bf16 (w_qkv 1536x512, w_proj 512x512)
// ---------------------------------------------------------------------------
__global__ __launch_bounds__(256) void convert_w_kernel(
    const float* __restrict__ wq, const float* __restrict__ wp,
    bf16* __restrict__ wqb, bf16* __restrict__ wpb)
{
    int ch = blockIdx.x * 256 + threadIdx.x;
    float4 v;
    bf16* dst;
    if (ch < 196608) {
        v = ((const float4*)wq)[ch];
        dst = wqb + ch * 4;
    } else {
        int c2 = ch - 196608;
        v = ((const float4*)wp)[c2];
        dst = wpb + c2 * 4;
    }
    bf16 o[4] = {f2b(v.x), f2b(v.y), f2b(v.z), f2b(v.w)};
    *(uint2*)dst = *(const uint2*)o;
}

// ---------------------------------------------------------------------------
// Kernel 1a: GroupNorm partial sums. 512 blocks for full-BW read.
// ---------------------------------------------------------------------------
__global__ __launch_bounds__(256) void gn_partial_kernel(
    const float* __restrict__ x,
    float* __restrict__ partS, float* __restrict__ partQ)
{
    const int bid = blockIdx.x;             // 0..511
    const size_t base = (size_t)bid * 16384;
    const int t = threadIdx.x;

    float sum = 0.f, ssq = 0.f;
    const float4* x4 = (const float4*)(x + base);
    for (int i = t; i < 4096; i += 256) {
        float4 v = x4[i];
        sum += v.x + v.y + v.z + v.w;
        ssq += v.x * v.x + v.y * v.y + v.z * v.z + v.w * v.w;
    }
    #pragma unroll
    for (int off = 32; off > 0; off >>= 1) {
        sum += __shfl_down(sum, off);
        ssq += __shfl_down(ssq, off);
    }
    __shared__ float red[8];
    const int wid = t >> 6, lane = t & 63;
    if (lane == 0) { red[wid] = sum; red[4 + wid] = ssq; }
    __syncthreads();
    if (t == 0) {
        partS[bid] = red[0] + red[1] + red[2] + red[3];
        partQ[bid] = red[4] + red[5] + red[6] + red[7];
    }
}

// Kernel 1b: finalize -> per-(b,c) scale/shift.
__global__ __launch_bounds__(64) void gn_finalize_kernel(
    const float* __restrict__ partS, const float* __restrict__ partQ,
    const float* __restrict__ gamma, const float* __restrict__ beta,
    float* __restrict__ scaleB, float* __restrict__ shiftB)
{
    const int bg = blockIdx.x;              // 0..127
    const int b = bg >> 3, g = bg & 7;
    const int t = threadIdx.x;              // 0..63
    float s = partS[bg * 4] + partS[bg * 4 + 1] + partS[bg * 4 + 2] + partS[bg * 4 + 3];
    float q = partQ[bg * 4] + partQ[bg * 4 + 1] + partQ[bg * 4 + 2] + partQ[bg * 4 + 3];
    float mean = s * (1.f / 65536.f);
    float var  = q * (1.f / 65536.f) - mean * mean;
    float rstd = rsqrtf(var + 1e-5f);
    int c = g * 64 + t;
    float sc = rstd * gamma[c];
    scaleB[b * 512 + c] = sc;
    shiftB[b * 512 + c] = beta[c] - mean * sc;
}

// ---------------------------------------------------------------------------
// Kernel 2: apply GN + transpose: x[b,c,l] f32 -> Xt[b,l,c] bf16.
// ---------------------------------------------------------------------------
__global__ __launch_bounds__(256) void gn_apply_t_kernel(
    const float* __restrict__ x,
    const float* __restrict__ scaleB,
    const float* __restrict__ shiftB,
    bf16* __restrict__ Xt)          // [16,1024,512]
{
    const int lt = blockIdx.x, ct = blockIdx.y, b = blockIdx.z;
    const int l0 = lt * 64, c0 = ct * 64;
    const int t = threadIdx.x;
    __shared__ float Ls[64][65];

    const float* xb = x + ((size_t)b * 512 + c0) * 1024 + l0;
    for (int i = t; i < 1024; i += 256) {
        int cc = i >> 4, lc = (i & 15) * 4;
        float4 v = *(const float4*)(xb + (size_t)cc * 1024 + lc);
        float sc = scaleB[b * 512 + c0 + cc];
        float sh = shiftB[b * 512 + c0 + cc];
        Ls[cc][lc]     = v.x * sc + sh;
        Ls[cc][lc + 1] = v.y * sc + sh;
        Ls[cc][lc + 2] = v.z * sc + sh;
        Ls[cc][lc + 3] = v.w * sc + sh;
    }
    __syncthreads();
    for (int i = t; i < 1024; i += 256) {
        int l = i >> 4, cc = (i & 15) * 4;
        bf16 o[4] = {f2b(Ls[cc][l]), f2b(Ls[cc + 1][l]),
                     f2b(Ls[cc + 2][l]), f2b(Ls[cc + 3][l])};
        *(uint2*)(Xt + ((size_t)b * 1024 + l0 + l) * 512 + c0 + cc) = *(const uint2*)o;
    }
}

// ---------------------------------------------------------------------------
// Kernel 3: QKV MFMA GEMM, 128x128 tile, BK=32, register-prefetch pipeline.
//   m-tiles 0-3 -> Qt[b][h][l][d], 4-7 -> Kt[b][h][m][d], 8-11 -> Vb[b][d][l]
// ---------------------------------------------------------------------------
__global__ __launch_bounds__(256) void mfma_qkv_kernel(
    const bf16* __restrict__ W,     // [1536,512]
    const bf16* __restrict__ Xt,    // [16,1024,512]
    const float* __restrict__ bias, // [1536]
    bf16* __restrict__ Qt,          // [16,4,1024,128]
    bf16* __restrict__ Kt,          // [16,4,1024,128]
    bf16* __restrict__ Vb)          // [16,512,1024]
{
    const int n0 = blockIdx.x * 128;
    const int m0 = blockIdx.y * 128;
    const int b  = blockIdx.z;
    const int t  = threadIdx.x;
    const int w  = t >> 6, lane = t & 63;
    const int c  = lane & 15, quad = lane >> 4;
    const int w0 = w & 1, w1 = w >> 1;
    const int ak = quad * 8;

    __shared__ __align__(16) bf16 smem[17408];
    bf16* As = smem;                // [128][40]
    bf16* Bs = smem + 5120;         // [128][40]
    bf16* Cs = smem;                // [128][136]

    const bf16* Ag = W + (size_t)m0 * 512;
    const bf16* Bg = Xt + ((size_t)b * 1024 + n0) * 512;

    const int srow = t >> 2, skc = (t & 3) * 8;

    short8 areg[2], breg[2];
    #pragma unroll
    for (int it = 0; it < 2; it++) {
        int row = srow + it * 64;
        areg[it] = *(const short8*)(Ag + (size_t)row * 512 + skc);
        breg[it] = *(const short8*)(Bg + (size_t)row * 512 + skc);
    }

    f32x4 acc[4][4];
    #pragma unroll
    for (int i = 0; i < 4; i++)
        #pragma unroll
        for (int j = 0; j < 4; j++)
            #pragma unroll
            for (int r = 0; r < 4; r++) acc[i][j][r] = 0.f;

    for (int k0 = 0; k0 < 512; k0 += 32) {
        __syncthreads();
        #pragma unroll
        for (int it = 0; it < 2; it++) {
            int row = srow + it * 64;
            *(short8*)&As[row * 40 + skc] = areg[it];
            *(short8*)&Bs[row * 40 + skc] = breg[it];
        }
        __syncthreads();
        {
            int k1 = (k0 + 32) & 511;
            #pragma unroll
            for (int it = 0; it < 2; it++) {
                int row = srow + it * 64;
                areg[it] = *(const short8*)(Ag + (size_t)row * 512 + k1 + skc);
                breg[it] = *(const short8*)(Bg + (size_t)row * 512 + k1 + skc);
            }
        }
        short8 af[4], bf[4];
        #pragma unroll
        for (int jm = 0; jm < 4; jm++)
            af[jm] = *(const short8*)&As[(w0 * 64 + jm * 16 + c) * 40 + ak];
        #pragma unroll
        for (int jn = 0; jn < 4; jn++)
            bf[jn] = *(const short8*)&Bs[(w1 * 64 + jn * 16 + c) * 40 + ak];
        #pragma unroll
        for (int jm = 0; jm < 4; jm++)
            #pragma unroll
            for (int jn = 0; jn < 4; jn++)
                acc[jm][jn] = __builtin_amdgcn_mfma_f32_16x16x32_bf16(
                    af[jm], bf[jn], acc[jm][jn], 0, 0, 0);
    }

    __syncthreads();
    const int cls = m0 >> 9;        // 0=Q, 1=K, 2=V
    if (cls < 2) {
        #pragma unroll
        for (int jm = 0; jm < 4; jm++) {
            #pragma unroll
            for (int jn = 0; jn < 4; jn++) {
                bf16 o4[4];
                #pragma unroll
                for (int r = 0; r < 4; r++) {
                    int orow = w0 * 64 + jm * 16 + quad * 4 + r;
                    o4[r] = f2b(acc[jm][jn][r] + bias[m0 + orow]);
                }
                *(uint2*)&Cs[(size_t)(w1 * 64 + jn * 16 + c) * 136
                             + w0 * 64 + jm * 16 + quad * 4] = *(const uint2*)o4;
            }
        }
        __syncthreads();
        const int head = (m0 >> 7) & 3;
        bf16* Db = (cls == 0 ? Qt : Kt)
                   + (((size_t)(b * 4 + head)) * 1024 + n0) * 128;
        for (int i = t; i < 2048; i += 256) {
            int row = i >> 4, ch = (i & 15) * 8;
            *(short8*)(Db + (size_t)row * 128 + ch) = *(const short8*)&Cs[row * 136 + ch];
        }
    } else {
        #pragma unroll
        for (int jm = 0; jm < 4; jm++) {
            #pragma unroll
            for (int r = 0; r < 4; r++) {
                int orow = w0 * 64 + jm * 16 + quad * 4 + r;
                float bs = bias[m0 + orow];
                #pragma unroll
                for (int jn = 0; jn < 4; jn++)
                    Cs[orow * 136 + w1 * 64 + jn * 16 + c] = f2b(acc[jm][jn][r] + bs);
            }
        }
        __syncthreads();
        bf16* Cb = Vb + ((size_t)b * 512 + (m0 - 1024)) * 1024 + n0;
        for (int i = t; i < 2048; i += 256) {
            int row = i >> 4, ch = (i & 15) * 8;
            *(short8*)(Cb + (size_t)row * 1024 + ch) = *(const short8*)&Cs[row * 136 + ch];
        }
    }
}

// ---------------------------------------------------------------------------
// Kernel 4: MFMA flash attention, 32x32x16, 512 threads / 8 waves.
// Wave pair (w, w+4): same 32 q-rows, split m-halves of each 64-key tile.
// Fixed-shift softmax (exp(s-6), exact partial combine), register-prefetched
// K/V, XCD-local grid. Exact LDS f32 combine in epilogue.
// 32x32x16 layouts: A/B row=lane&31, k=(lane>>5)*8+j.
//                   C/D col=lane&31, row=(reg&3)+8*(reg>>2)+4*(lane>>5).
// ---------------------------------------------------------------------------
#define HD 128
#define QT 128
#define MT 64
#define SM_SHIFT 6.0f

__global__ __launch_bounds__(512, 4) void attn_mfma_kernel(
    const bf16* __restrict__ Qt,    // [16,4,1024,128]
    const bf16* __restrict__ Kt,    // [16,4,1024,128]
    const bf16* __restrict__ Vb,    // [16,512,1024]
    bf16* __restrict__ out)         // [16,1024,512]
{
    const int bh = blockIdx.x;      // 0..63 (XCD = bh % 8)
    const int qt = blockIdx.y;      // 0..7
    const int b = bh >> 2, h = bh & 3;
    const int t = threadIdx.x;      // 0..511
    const int w8 = t >> 6;          // 0..7
    const int w  = w8 & 3;          // q-strip
    const int mh = w8 >> 2;         // m-half 0/1
    const int lane = t & 63;
    const int wrow = lane & 31;
    const int blk  = lane >> 5;
    const int l0 = qt * QT;

    __shared__ __align__(16) bf16 smem[27136];  // 54272 B
    bf16* Ks = smem;            // [64][136]
    bf16* Vs = smem + 8704;     // [128][72]
    bf16* Ps = smem + 17920;    // [128][72]

    // Q fragments: wave pair (w,*) owns q-rows [w*32, w*32+32)
    const int qrow = w * 32 + wrow;
    const bf16* Qr = Qt + (((size_t)(b * 4 + h)) * 1024 + l0 + qrow) * 128;
    short8 aq[8];
    #pragma unroll
    for (int kt = 0; kt < 8; kt++)
        aq[kt] = *(const short8*)(Qr + kt * 16 + blk * 8);

    const bf16* Kb = Kt + (((size_t)(b * 4 + h)) * 1024) * 128;
    const bf16* Vg = Vb + ((size_t)(b * 512 + h * HD)) * 1024;

    short8 kreg[2], vreg[2];
    #pragma unroll
    for (int p = 0; p < 2; p++) {
        int i = t + p * 512;
        kreg[p] = *(const short8*)(Kb + (size_t)(i >> 4) * 128 + (i & 15) * 8);
        vreg[p] = *(const short8*)(Vg + (size_t)(i >> 3) * 1024 + (i & 7) * 8);
    }

    f32x16 acc_o[4];
    #pragma unroll
    for (int n = 0; n < 4; n++)
        #pragma unroll
        for (int r = 0; r < 16; r++) acc_o[n][r] = 0.f;

    float psum[16];
    #pragma unroll
    for (int r = 0; r < 16; r++) psum[r] = 0.f;

    const float scale = 0.08838834764831845f;   // 128^-0.5

    for (int mt = 0; mt < 1024 / MT; mt++) {
        __syncthreads();    // prev iter's LDS reads done

        #pragma unroll
        for (int p = 0; p < 2; p++) {
            int i = t + p * 512;
            *(short8*)&Ks[(i >> 4) * 136 + (i & 15) * 8] = kreg[p];
            *(short8*)&Vs[(i >> 3) * 72 + (i & 7) * 8]   = vreg[p];
        }
        __syncthreads();    // LDS visible

        {   // prefetch next tile (wraps harmlessly on last iter)
            int m0n = (mt < 15) ? (mt + 1) * MT : 0;
            #pragma unroll
            for (int p = 0; p < 2; p++) {
                int i = t + p * 512;
                kreg[p] = *(const short8*)(Kb + (size_t)(m0n + (i >> 4)) * 128 + (i & 15) * 8);
                vreg[p] = *(const short8*)(Vg + (size_t)(i >> 3) * 1024 + m0n + (i & 7) * 8);
            }
        }

        // ---- S = Q K^T : this wave's m-half (32 keys), 8 k-steps
        f32x16 accs;
        #pragma unroll
        for (int r = 0; r < 16; r++) accs[r] = 0.f;
        #pragma unroll
        for (int kt = 0; kt < 8; kt++) {
            short8 bfr = *(const short8*)&Ks[(mh * 32 + wrow) * 136 + kt * 16 + blk * 8];
            accs = __builtin_amdgcn_mfma_f32_32x32x16_bf16(aq[kt], bfr, accs, 0, 0, 0);
        }

        // ---- softmax numerator: p = exp(s*scale - 6); row-sums deferred
        #pragma unroll
        for (int r = 0; r < 16; r++) {
            float p = __expf(accs[r] * scale - SM_SHIFT);
            psum[r] += p;
            int row = w * 32 + (r & 3) + 8 * (r >> 2) + 4 * blk;
            Ps[row * 72 + mh * 32 + wrow] = f2b(p);
        }

        // ---- PV over this wave's m-half (P cols are wave-private: no barrier)
        #pragma unroll
        for (int kt2 = 0; kt2 < 2; kt2++) {
            short8 a = *(const short8*)&Ps[(w * 32 + wrow) * 72 + (mh * 2 + kt2) * 16 + blk * 8];
            #pragma unroll
            for (int nt2 = 0; nt2 < 4; nt2++) {
                short8 bv = *(const short8*)&Vs[(nt2 * 32 + wrow) * 72 + (mh * 2 + kt2) * 16 + blk * 8];
                acc_o[nt2] = __builtin_amdgcn_mfma_f32_32x32x16_bf16(a, bv, acc_o[nt2], 0, 0, 0);
            }
        }
    }

    // ---- epilogue: reduce psum over this half's 32 cols
    #pragma unroll
    for (int off = 1; off < 32; off <<= 1)
        #pragma unroll
        for (int r = 0; r < 16; r++)
            psum[r] += __shfl_xor(psum[r], off);

    // combine wave pairs via LDS (exact f32), two d-chunks of 64
    float* comb = (float*)smem;         // [128][68] = 8704 floats
    float* psumArr = comb + 8704;       // [128]
    __syncthreads();                    // all K/V/P reads done

    #pragma unroll
    for (int half = 0; half < 2; half++) {
        if (mh == 1) {
            #pragma unroll
            for (int n2 = 0; n2 < 2; n2++)
                #pragma unroll
                for (int r = 0; r < 16; r++) {
                    int row = w * 32 + (r & 3) + 8 * (r >> 2) + 4 * blk;
                    comb[row * 68 + n2 * 32 + wrow] = acc_o[half * 2 + n2][r];
                }
            if (half == 0 && wrow == 0)
                #pragma unroll
                for (int r = 0; r < 16; r++) {
                    int row = w * 32 + (r & 3) + 8 * (r >> 2) + 4 * blk;
                    psumArr[row] = psum[r];
                }
        }
        __syncthreads();
        if (mh == 0) {
            #pragma unroll
            for (int n2 = 0; n2 < 2; n2++)
                #pragma unroll
                for (int r = 0; r < 16; r++) {
                    int row = w * 32 + (r & 3) + 8 * (r >> 2) + 4 * blk;
                    acc_o[half * 2 + n2][r] += comb[row * 68 + n2 * 32 + wrow];
                }
            if (half == 0)
                #pragma unroll
                for (int r = 0; r < 16; r++) {
                    int row = w * 32 + (r & 3) + 8 * (r >> 2) + 4 * blk;
                    psum[r] += psumArr[row];
                }
        }
        __syncthreads();
    }

    // normalize + stage Os[l][d] bf16 (waves mh==0), coalesced store (all)
    bf16* Os = smem;                    // [128][136]
    if (mh == 0) {
        float inv[16];
        #pragma unroll
        for (int r = 0; r < 16; r++) inv[r] = 1.f / psum[r];
        #pragma unroll
        for (int nt2 = 0; nt2 < 4; nt2++)
            #pragma unroll
            for (int r = 0; r < 16; r++) {
                int row = w * 32 + (r & 3) + 8 * (r >> 2) + 4 * blk;
                Os[row * 136 + nt2 * 32 + wrow] = f2b(acc_o[nt2][r] * inv[r]);
            }
    }
    __syncthreads();
    bf16* Ob = out + ((size_t)b * 1024 + l0) * 512 + h * HD;
    for (int i = t; i < 2048; i += 512) {
        int row = i >> 4, ch = (i & 15) * 8;
        *(short8*)(Ob + (size_t)row * 512 + ch) = *(const short8*)&Os[row * 136 + ch];
    }
}

// ---------------------------------------------------------------------------
// Kernel 5: proj GEMM + bias + residual, f32 out, register-prefetch pipeline.
// ---------------------------------------------------------------------------
__global__ __launch_bounds__(256) void mfma_proj_kernel(
    const bf16* __restrict__ W,     // [512,512]
    const bf16* __restrict__ Xt,    // [16,1024,512] (attn_t)
    const float* __restrict__ bias, // [512]
    const float* __restrict__ res,  // [16,512,1024]
    float* __restrict__ C)          // [16,512,1024]
{
    const int n0 = blockIdx.x * 128;
    const int m0 = blockIdx.y * 128;
    const int b  = blockIdx.z;
    const int t  = threadIdx.x;
    const int w  = t >> 6, lane = t & 63;
    const int c  = lane & 15, quad = lane >> 4;
    const int w0 = w & 1, w1 = w >> 1;
    const int ak = quad * 8;

    __shared__ __align__(16) bf16 smem[17408];
    bf16* As = smem;
    bf16* Bs = smem + 5120;
    bf16* Cs = smem;

    const bf16* Ag = W + (size_t)m0 * 512;
    const bf16* Bg = Xt + ((size_t)b * 1024 + n0) * 512;

    const int srow = t >> 2, skc = (t & 3) * 8;

    short8 areg[2], breg[2];
    #pragma unroll
    for (int it = 0; it < 2; it++) {
        int row = srow + it * 64;
        areg[it] = *(const short8*)(Ag + (size_t)row * 512 + skc);
        breg[it] = *(const short8*)(Bg + (size_t)row * 512 + skc);
    }

    f32x4 acc[4][4];
    #pragma unroll
    for (int i = 0; i < 4; i++)
        #pragma unroll
        for (int j = 0; j < 4; j++)
            #pragma unroll
            for (int r = 0; r < 4; r++) acc[i][j][r] = 0.f;

    for (int k0 = 0; k0 < 512; k0 += 32) {
        __syncthreads();
        #pragma unroll
        for (int it = 0; it < 2; it++) {
            int row = srow + it * 64;
            *(short8*)&As[row * 40 + skc] = areg[it];
            *(short8*)&Bs[row * 40 + skc] = breg[it];
        }
        __syncthreads();
        {
            int k1 = (k0 + 32) & 511;
            #pragma unroll
            for (int it = 0; it < 2; it++) {
                int row = srow + it * 64;
                areg[it] = *(const short8*)(Ag + (size_t)row * 512 + k1 + skc);
                breg[it] = *(const short8*)(Bg + (size_t)row * 512 + k1 + skc);
            }
        }
        short8 af[4], bf[4];
        #pragma unroll
        for (int jm = 0; jm < 4; jm++)
            af[jm] = *(const short8*)&As[(w0 * 64 + jm * 16 + c) * 40 + ak];
        #pragma unroll
        for (int jn = 0; jn < 4; jn++)
            bf[jn] = *(const short8*)&Bs[(w1 * 64 + jn * 16 + c) * 40 + ak];
        #pragma unroll
        for (int jm = 0; jm < 4; jm++)
            #pragma unroll
            for (int jn = 0; jn < 4; jn++)
                acc[jm][jn] = __builtin_amdgcn_mfma_f32_16x16x32_bf16(
                    af[jm], bf[jn], acc[jm][jn], 0, 0, 0);
    }

    __syncthreads();
    #pragma unroll
    for (int jm = 0; jm < 4; jm++) {
        #pragma unroll
        for (int r = 0; r < 4; r++) {
            int orow = w0 * 64 + jm * 16 + quad * 4 + r;
            float bs = bias[m0 + orow];
            #pragma unroll
            for (int jn = 0; jn < 4; jn++)
                Cs[orow * 136 + w1 * 64 + jn * 16 + c] = f2b(acc[jm][jn][r] + bs);
        }
    }
    __syncthreads();
    const float* Rb = res + ((size_t)b * 512 + m0) * 1024 + n0;
    float* Cb = C + ((size_t)b * 512 + m0) * 1024 + n0;
    for (int i = t; i < 4096; i += 256) {
        int row = i >> 5, ch = (i & 31) * 4;
        float4 rv = *(const float4*)(Rb + (size_t)row * 1024 + ch);
        float4 ov;
        ov.x = b2f(Cs[row * 136 + ch + 0]) + rv.x;
        ov.y = b2f(Cs[row * 136 + ch + 1]) + rv.y;
        ov.z = b2f(Cs[row * 136 + ch + 2]) + rv.z;
        ov.w = b2f(Cs[row * 136 + ch + 3]) + rv.w;
        *(float4*)(Cb + (size_t)row * 1024 + ch) = ov;
    }
}

// ---------------------------------------------------------------------------
extern "C" void kernel_launch(void* const* d_in, const int* in_sizes, int n_in,
                              void* d_out, int out_size, void* d_ws, size_t ws_size,
                              hipStream_t stream)
{
    const float* x      = (const float*)d_in[0];
    const float* gamma  = (const float*)d_in[1];
    const float* beta   = (const float*)d_in[2];
    const float* w_qkv  = (const float*)d_in[3];
    const float* b_qkv  = (const float*)d_in[4];
    const float* w_proj = (const float*)d_in[5];
    const float* b_proj = (const float*)d_in[6];
    float* out = (float*)d_out;

    char* ws = (char*)d_ws;
    float* scaleB = (float*)ws;                               // 32 KB
    float* shiftB = (float*)(ws + 32768);                     // 32 KB
    bf16*  wqb    = (bf16*)(ws + 65536);                      // 1.5 MB
    bf16*  wpb    = (bf16*)(ws + 65536 + 1572864);            // 0.5 MB
    char*  big    = ws + 65536 + 2097152;
    bf16*  Xt     = (bf16*)(big);                             // 16 MB [16,1024,512]
    bf16*  Qt     = (bf16*)(big + (size_t)16777216);          // 16 MB [16,4,1024,128]
    bf16*  Kt     = (bf16*)(big + (size_t)2 * 16777216);      // 16 MB
    bf16*  Vb     = (bf16*)(big + (size_t)3 * 16777216);      // 16 MB [16,512,1024]
    float* partS  = (float*)(big + (size_t)4 * 16777216);     // 2 KB
    float* partQ  = partS + 512;                              // 2 KB
    bf16*  attn_t = Xt;   // Xt dead after qkv GEMM; attention writes here

    hipLaunchKernelGGL(convert_w_kernel, dim3(1024), dim3(256), 0, stream,
                       w_qkv, w_proj, wqb, wpb);
    hipLaunchKernelGGL(gn_partial_kernel, dim3(512), dim3(256), 0, stream,
                       x, partS, partQ);
    hipLaunchKernelGGL(gn_finalize_kernel, dim3(128), dim3(64), 0, stream,
                       partS, partQ, gamma, beta, scaleB, shiftB);
    hipLaunchKernelGGL(gn_apply_t_kernel, dim3(16, 8, 16), dim3(256), 0, stream,
                       x, scaleB, shiftB, Xt);
    hipLaunchKernelGGL(mfma_qkv_kernel, dim3(8, 12, 16), dim3(256), 0, stream,
                       wqb, Xt, b_qkv, Qt, Kt, Vb);
    hipLaunchKernelGGL(attn_mfma_kernel, dim3(64, 8), dim3(512), 0, stream,
                       Qt, Kt, Vb, attn_t);
    hipLaunchKernelGGL(mfma_proj_kernel, dim3(8, 4, 16), dim3(256), 0, stream,
                       wpb, attn_t, b_proj, x, out);
}